// Round 9
// baseline (855.868 us; speedup 1.0000x reference)
//
#include <hip/hip_runtime.h>
#include <math.h>

#define N_NODES  100000
#define N_EDGES  3200000
#define K_IN     1433
#define NH       16
#define NO       7

#define TK       16
#define KSPLIT   9
#define CPS      10                           // chunks per split (9*10*16 = 1440 >= 1433)
#define RW       (CPS * TK)                   // 160 W1 rows per split
#define RPT      4                            // rows per thread
#define TROWS    (64 * RPT)                   // 256 rows per wave-tile
#define NTILE4   ((N_NODES + TROWS - 1) / TROWS)  // 391
#define NRB4     ((NTILE4 + 3) / 4)               // 98 row-blocks (4 tiles/block)
#define SLOT     96                           // adjacency slots per node

typedef float f4  __attribute__((ext_vector_type(4)));
typedef float f4u __attribute__((ext_vector_type(4), aligned(4)));

// ---------------- K1: single-pass build (deg_out, deg_in/cursor, slotted adj) ----
__global__ __launch_bounds__(256)
void k_build(const int* __restrict__ src, const int* __restrict__ dst,
             int* __restrict__ deg_out, int* __restrict__ cnt,
             int* __restrict__ adj) {
    int i = blockIdx.x * blockDim.x + threadIdx.x;
    int stride = gridDim.x * blockDim.x;
    for (; i < N_EDGES; i += stride) {
        int s = src[i], d = dst[i];
        atomicAdd(&deg_out[s], 1);
        int p = atomicAdd(&cnt[d], 1);
        if (p < SLOT) adj[d * SLOT + p] = s;
    }
}

// ---------------- K2: hpart[split] = X[:, ksplit] @ W1[ksplit, :] ----------------
// RPT=4 rows/thread, SINGLE register buffer (16 f4), ROLLED chunk loop
// (#pragma unroll 1 -- full unroll caused 256-VGPR scratch spill in R6/R7).
// W slice in LDS, read as wave-uniform ds_read_b128 broadcasts amortized over
// 4 rows/thread: LDS pipe demand 44us < 91us HBM floor.

#define LOADR_FULL(PTR, KN, R0, R1, R2, R3)                \
  { R0 = *(const f4u*)((PTR) + (KN));                      \
    R1 = *(const f4u*)((PTR) + (KN) + 4);                  \
    R2 = *(const f4u*)((PTR) + (KN) + 8);                  \
    R3 = *(const f4u*)((PTR) + (KN) + 12); }

// tail chunk (k=1424..1439): last valid k is 1432; W rows >=1433 are zero in
// LDS so the zeroed x slots are dead anyway.
#define LOADR_TAIL(PTR, KN, R0, R1, R2, R3)                \
  { R0 = *(const f4u*)((PTR) + (KN));                      \
    R1 = *(const f4u*)((PTR) + (KN) + 4);                  \
    R2 = 0.f; R2[0] = (PTR)[(KN) + 8];                     \
    R3 = 0.f; }

#define CH_FMA(CC)                                                      \
  { const float* wb = wlds + (CC) * (TK * NH);                          \
    _Pragma("unroll")                                                   \
    for (int kk = 0; kk < TK; ++kk) {                                   \
      const f4 va = (kk < 4) ? a0 : (kk < 8) ? a1 : (kk < 12) ? a2 : a3;\
      const f4 vb = (kk < 4) ? b0 : (kk < 8) ? b1 : (kk < 12) ? b2 : b3;\
      const f4 vc = (kk < 4) ? c0 : (kk < 8) ? c1 : (kk < 12) ? c2 : c3;\
      const f4 vd = (kk < 4) ? d0 : (kk < 8) ? d1 : (kk < 12) ? d2 : d3;\
      const float xa = va[kk & 3], xb = vb[kk & 3];                     \
      const float xc = vc[kk & 3], xd = vd[kk & 3];                     \
      const f4* wr = (const f4*)(wb + kk * NH);                         \
      const f4 w0 = wr[0], w1 = wr[1], w2 = wr[2], w3 = wr[3];          \
      accA0 += xa * w0; accA1 += xa * w1; accA2 += xa * w2; accA3 += xa * w3; \
      accB0 += xb * w0; accB1 += xb * w1; accB2 += xb * w2; accB3 += xb * w3; \
      accC0 += xc * w0; accC1 += xc * w1; accC2 += xc * w2; accC3 += xc * w3; \
      accD0 += xd * w0; accD1 += xd * w1; accD2 += xd * w2; accD3 += xd * w3; \
    } }

__global__ __launch_bounds__(256)
void k_gemm1(const float* __restrict__ X, const float* __restrict__ W1,
             float* __restrict__ hpart) {
    __shared__ float wlds[RW * NH];            // 10240 B = 640 f4
    const int wid = threadIdx.x >> 6;
    const int t   = threadIdx.x & 63;
    const int rb    = blockIdx.x % NRB4;
    const int split = blockIdx.x / NRB4;

    // ---- stage this split's W1 slice into LDS (zero-fill past K_IN) ----
    {
        const f4* W1v = (const f4*)W1;         // each W1 row = 4 f4
        const int wbase = split * RW;
#pragma unroll
        for (int r = 0; r < 3; ++r) {          // ceil(640/256) = 3 iters
            int idx = r * 256 + threadIdx.x;   // f4 index into wlds
            if (idx < RW * 4) {
                int krow = wbase + (idx >> 2);
                f4 wv = 0.f;
                if (krow < K_IN) wv = W1v[krow * 4 + (idx & 3)];
                ((f4*)wlds)[idx] = wv;
            }
        }
    }
    __syncthreads();

    const int tile = rb * 4 + wid;
    if (tile >= NTILE4) return;                // wave-uniform, after the sync
    const int base = tile * TROWS;
    const int r0 = min(base + t,       N_NODES - 1);
    const int r1 = min(base + 64 + t,  N_NODES - 1);
    const int r2 = min(base + 128 + t, N_NODES - 1);
    const int r3 = min(base + 192 + t, N_NODES - 1);
    const float* xr0 = X + (size_t)r0 * K_IN;
    const float* xr1 = X + (size_t)r1 * K_IN;
    const float* xr2 = X + (size_t)r2 * K_IN;
    const float* xr3 = X + (size_t)r3 * K_IN;

    f4 accA0 = 0.f, accA1 = 0.f, accA2 = 0.f, accA3 = 0.f;
    f4 accB0 = 0.f, accB1 = 0.f, accB2 = 0.f, accB3 = 0.f;
    f4 accC0 = 0.f, accC1 = 0.f, accC2 = 0.f, accC3 = 0.f;
    f4 accD0 = 0.f, accD1 = 0.f, accD2 = 0.f, accD3 = 0.f;

    f4 a0, a1, a2, a3, b0, b1, b2, b3;
    f4 c0v, c1v, c2v, c3v, d0, d1, d2, d3;
#define c0 c0v
#define c1 c1v
#define c2 c2v
#define c3 c3v

    const int cs0 = split * CPS;
#pragma unroll 1
    for (int cc = 0; cc < CPS; ++cc) {
        const int kn = (cs0 + cc) * TK;
        if (kn + TK <= K_IN) {                 // wave-uniform; all but chunk 89
            LOADR_FULL(xr0, kn, a0, a1, a2, a3)
            LOADR_FULL(xr1, kn, b0, b1, b2, b3)
            LOADR_FULL(xr2, kn, c0, c1, c2, c3)
            LOADR_FULL(xr3, kn, d0, d1, d2, d3)
        } else {
            LOADR_TAIL(xr0, kn, a0, a1, a2, a3)
            LOADR_TAIL(xr1, kn, b0, b1, b2, b3)
            LOADR_TAIL(xr2, kn, c0, c1, c2, c3)
            LOADR_TAIL(xr3, kn, d0, d1, d2, d3)
        }
        CH_FMA(cc)
    }
#undef c0
#undef c1
#undef c2
#undef c3

    const size_t sb = (size_t)split * N_NODES;
    if (base + t < N_NODES) {
        f4* hp = (f4*)(hpart + (sb + r0) * NH);
        hp[0] = accA0; hp[1] = accA1; hp[2] = accA2; hp[3] = accA3;
    }
    if (base + 64 + t < N_NODES) {
        f4* hp = (f4*)(hpart + (sb + r1) * NH);
        hp[0] = accB0; hp[1] = accB1; hp[2] = accB2; hp[3] = accB3;
    }
    if (base + 128 + t < N_NODES) {
        f4* hp = (f4*)(hpart + (sb + r2) * NH);
        hp[0] = accC0; hp[1] = accC1; hp[2] = accC2; hp[3] = accC3;
    }
    if (base + 192 + t < N_NODES) {
        f4* hp = (f4*)(hpart + (sb + r3) * NH);
        hp[0] = accD0; hp[1] = accD1; hp[2] = accD2; hp[3] = accD3;
    }
}

// ---------------- K3: h = norm_src * sum_s hpart[s] ----------------
__global__ __launch_bounds__(256)
void k_reduce(const float* __restrict__ hpart, const int* __restrict__ deg_out,
              float* __restrict__ h) {
    int idx = blockIdx.x * 256 + threadIdx.x;   // f4 index
    if (idx >= N_NODES * 4) return;
    f4 a = 0.f;
#pragma unroll
    for (int s = 0; s < KSPLIT; ++s)
        a += ((const f4*)hpart)[(size_t)s * N_NODES * 4 + idx];
    float ns = rsqrtf((float)max(deg_out[idx >> 2], 1));
    ((f4*)h)[idx] = a * ns;
}

// ---------------- K4: gather layer1 + relu + fused (.. @ W2) ----------------
__global__ __launch_bounds__(256)
void k_layer1(const float* __restrict__ h, const int* __restrict__ adj,
              const int* __restrict__ cnt, const int* __restrict__ deg_out,
              const float* __restrict__ W2, const float* __restrict__ b1,
              float* __restrict__ g) {
    const int lane = threadIdx.x & 63;
    const int wid  = threadIdx.x >> 6;
    const int d    = blockIdx.x * 4 + wid;
    if (d >= N_NODES) return;                  // wave-uniform
    const int j4 = lane & 3, slot = lane >> 2;
    const int start = d * SLOT;
    const int deg   = min(cnt[d], SLOT);
    const int end   = start + deg;
    f4 agg = 0.f;
    for (int p = start + slot; p < end; p += 16) {
        int s = adj[p];
        agg += ((const f4*)h)[s * 4 + j4];
    }
#pragma unroll
    for (int off = 4; off < 64; off <<= 1) {
        agg[0] += __shfl_xor(agg[0], off);
        agg[1] += __shfl_xor(agg[1], off);
        agg[2] += __shfl_xor(agg[2], off);
        agg[3] += __shfl_xor(agg[3], off);
    }
    __shared__ float st[4][NH];
    const float nd = rsqrtf((float)max(deg, 1));
    if (slot == 0) {
        f4 bb = ((const f4*)b1)[j4];
        f4 tj;
        tj[0] = fmaxf(fmaf(agg[0], nd, bb[0]), 0.f);
        tj[1] = fmaxf(fmaf(agg[1], nd, bb[1]), 0.f);
        tj[2] = fmaxf(fmaf(agg[2], nd, bb[2]), 0.f);
        tj[3] = fmaxf(fmaf(agg[3], nd, bb[3]), 0.f);
        ((f4*)st[wid])[j4] = tj;
    }
    __builtin_amdgcn_wave_barrier();
    float r = 0.f;
    if (lane < NO) {
#pragma unroll
        for (int qq = 0; qq < NH; ++qq)
            r = fmaf(st[wid][qq], W2[qq * NO + lane], r);
    }
    if (lane < 8) {
        float ns = rsqrtf((float)max(deg_out[d], 1));
        g[(size_t)d * 8 + lane] = (lane < NO) ? ns * r : 0.f;  // zero pad slot
    }
}

// ---------------- K5: gather layer2 -> out ----------------
__global__ __launch_bounds__(256)
void k_layer2(const float* __restrict__ g, const int* __restrict__ adj,
              const int* __restrict__ cnt, const float* __restrict__ b2,
              float* __restrict__ out) {
    const int lane = threadIdx.x & 63;
    const int wid  = threadIdx.x >> 6;
    const int d    = blockIdx.x * 4 + wid;
    if (d >= N_NODES) return;
    const int o4 = lane & 1, slot = lane >> 1;
    const int start = d * SLOT;
    const int deg   = min(cnt[d], SLOT);
    const int end   = start + deg;
    f4 agg = 0.f;
    for (int p = start + slot; p < end; p += 32) {
        int s = adj[p];
        agg += ((const f4*)g)[s * 2 + o4];
    }
#pragma unroll
    for (int off = 2; off < 64; off <<= 1) {
        agg[0] += __shfl_xor(agg[0], off);
        agg[1] += __shfl_xor(agg[1], off);
        agg[2] += __shfl_xor(agg[2], off);
        agg[3] += __shfl_xor(agg[3], off);
    }
    // even lanes hold o=0..3 sums, odd lanes hold o=4..7 sums
    const int sl = lane >> 2;
    float v0 = __shfl(agg[0], sl);
    float v1 = __shfl(agg[1], sl);
    float v2 = __shfl(agg[2], sl);
    float v3 = __shfl(agg[3], sl);
    int cm = lane & 3;
    float v = (cm == 0) ? v0 : (cm == 1) ? v1 : (cm == 2) ? v2 : v3;
    if (lane < NO) {
        float nd = rsqrtf((float)max(deg, 1));
        out[(size_t)d * NO + lane] = fmaf(v, nd, b2[lane]);
    }
}

extern "C" void kernel_launch(void* const* d_in, const int* in_sizes, int n_in,
                              void* d_out, int out_size, void* d_ws, size_t ws_size,
                              hipStream_t stream) {
    const float* X   = (const float*)d_in[0];
    const int*   src = (const int*)d_in[1];
    const int*   dst = (const int*)d_in[2];
    const float* W1  = (const float*)d_in[3];
    const float* b1  = (const float*)d_in[4];
    const float* W2  = (const float*)d_in[5];
    const float* b2  = (const float*)d_in[6];
    float* out = (float*)d_out;

    char* w = (char*)d_ws;
    float* hpart    = (float*)w;  w += (size_t)KSPLIT * N_NODES * NH * 4; // 57.6 MB
    float* h        = (float*)w;  w += (size_t)N_NODES * NH * 4;          // 6.4 MB
    float* g        = (float*)w;  w += (size_t)N_NODES * 8 * 4;           // 3.2 MB
    int*   adj      = (int*)w;    w += (size_t)N_NODES * SLOT * 4;        // 38.4 MB
    int*   deg_out_a= (int*)w;    w += (size_t)N_NODES * 4;
    int*   cnt      = (int*)w;    w += (size_t)N_NODES * 4;

    hipMemsetAsync(deg_out_a, 0, (size_t)N_NODES * 2 * 4, stream);

    k_build <<<2048, 256, 0, stream>>>(src, dst, deg_out_a, cnt, adj);
    k_gemm1 <<<NRB4 * KSPLIT, 256, 0, stream>>>(X, W1, hpart);
    k_reduce<<<(N_NODES * 4 + 255) / 256, 256, 0, stream>>>(hpart, deg_out_a, h);
    k_layer1<<<(N_NODES + 3) / 4, 256, 0, stream>>>(h, adj, cnt, deg_out_a,
                                                    W2, b1, g);
    k_layer2<<<(N_NODES + 3) / 4, 256, 0, stream>>>(g, adj, cnt, b2, out);
}

// Round 10
// 585.981 us; speedup vs baseline: 1.4606x; 1.4606x over previous
//
#include <hip/hip_runtime.h>
#include <math.h>

#define N_NODES  100000
#define N_EDGES  3200000
#define K_IN     1433
#define NH       16
#define NO       7

#define TK       16
#define KSPLIT   9
#define CPS      10                           // chunks per split (9*10*16 = 1440 >= 1433)
#define RW       (CPS * TK)                   // 160 W1 rows per split
#define TILE_R   128                          // rows per wave-tile
#define SXS      20                           // X-tile row stride (floats): 80B, 16B-aligned
#define NTILEV   ((N_NODES + TILE_R - 1) / TILE_R)   // 782
#define NRBV     ((NTILEV + 3) / 4)                  // 196 row-blocks (4 waves/block)
#define SLOT     96                           // adjacency slots per node

typedef float f4  __attribute__((ext_vector_type(4)));
typedef float f4u __attribute__((ext_vector_type(4), aligned(4)));

// ---------------- K1: single-pass build (deg_out, deg_in/cursor, slotted adj) ----
__global__ __launch_bounds__(256)
void k_build(const int* __restrict__ src, const int* __restrict__ dst,
             int* __restrict__ deg_out, int* __restrict__ cnt,
             int* __restrict__ adj) {
    int i = blockIdx.x * blockDim.x + threadIdx.x;
    int stride = gridDim.x * blockDim.x;
    for (; i < N_EDGES; i += stride) {
        int s = src[i], d = dst[i];
        atomicAdd(&deg_out[s], 1);
        int p = atomicAdd(&cnt[d], 1);
        if (p < SLOT) adj[d * SLOT + p] = s;
    }
}

// ---------------- K2: hpart[split] = X[:, ksplit] @ W1[ksplit, :] ----------------
// Coalesced X staging (4 lanes share a row's 64B -> small straddle window, no
// HBM over-fetch; R3-proven) through an LDS tile [128][SXS=20] with b128
// writes/reads (balanced bank positions). W slice in LDS, wave-uniform
// ds_read_b128 broadcasts amortized over 2 rows/thread. Rolled 2-chunk loop
// with NAMED P/Q prefetch sets (R8-proven: no scratch spill).

// stage one 16-k chunk of 128 rows into register set (8 granules/lane)
#define LOADG(KN, S0,S1,S2,S3,S4,S5,S6,S7)                               \
  { if ((KN) + TK <= K_IN) {                                             \
      S0 = *(const f4u*)(xp0 + (KN)); S1 = *(const f4u*)(xp1 + (KN));    \
      S2 = *(const f4u*)(xp2 + (KN)); S3 = *(const f4u*)(xp3 + (KN));    \
      S4 = *(const f4u*)(xp4 + (KN)); S5 = *(const f4u*)(xp5 + (KN));    \
      S6 = *(const f4u*)(xp6 + (KN)); S7 = *(const f4u*)(xp7 + (KN));    \
    } else {                                                             \
      /* tail chunk kn=1424: kq<2 full, kq==2 scalar k=1432, kq==3 zero */\
      S0=0.f;S1=0.f;S2=0.f;S3=0.f;S4=0.f;S5=0.f;S6=0.f;S7=0.f;           \
      if (Lq < 2) {                                                      \
        S0 = *(const f4u*)(xp0 + (KN)); S1 = *(const f4u*)(xp1 + (KN));  \
        S2 = *(const f4u*)(xp2 + (KN)); S3 = *(const f4u*)(xp3 + (KN));  \
        S4 = *(const f4u*)(xp4 + (KN)); S5 = *(const f4u*)(xp5 + (KN));  \
        S6 = *(const f4u*)(xp6 + (KN)); S7 = *(const f4u*)(xp7 + (KN));  \
      } else if (Lq == 2) {                                              \
        S0[0] = xp0[(KN)]; S1[0] = xp1[(KN)];                            \
        S2[0] = xp2[(KN)]; S3[0] = xp3[(KN)];                            \
        S4[0] = xp4[(KN)]; S5[0] = xp5[(KN)];                            \
        S6[0] = xp6[(KN)]; S7[0] = xp7[(KN)];                            \
      }                                                                  \
    } }

// write the 8 granules to the wave's LDS tile (compile-time offsets)
#define WRITE_SET(S0,S1,S2,S3,S4,S5,S6,S7)                               \
  { *(f4*)(xbw + 0*16*SXS) = S0; *(f4*)(xbw + 1*16*SXS) = S1;            \
    *(f4*)(xbw + 2*16*SXS) = S2; *(f4*)(xbw + 3*16*SXS) = S3;            \
    *(f4*)(xbw + 4*16*SXS) = S4; *(f4*)(xbw + 5*16*SXS) = S5;            \
    *(f4*)(xbw + 6*16*SXS) = S6; *(f4*)(xbw + 7*16*SXS) = S7; }

// read own 2 rows (16 k each) and FMA against W broadcasts
#define READ_FMA(CC)                                                     \
  { f4 xa0 = *(const f4*)(xra +  0), xa1 = *(const f4*)(xra +  4);       \
    f4 xa2 = *(const f4*)(xra +  8), xa3 = *(const f4*)(xra + 12);       \
    f4 xb0 = *(const f4*)(xrb +  0), xb1 = *(const f4*)(xrb +  4);       \
    f4 xb2 = *(const f4*)(xrb +  8), xb3 = *(const f4*)(xrb + 12);       \
    const float* wb = wlds + (CC) * (TK * NH);                           \
    _Pragma("unroll")                                                    \
    for (int kk = 0; kk < TK; ++kk) {                                    \
      const f4 va = (kk < 4) ? xa0 : (kk < 8) ? xa1 : (kk < 12) ? xa2 : xa3; \
      const f4 vb = (kk < 4) ? xb0 : (kk < 8) ? xb1 : (kk < 12) ? xb2 : xb3; \
      const float xa = va[kk & 3], xb = vb[kk & 3];                      \
      const f4* wr = (const f4*)(wb + kk * NH);                          \
      const f4 w0 = wr[0], w1 = wr[1], w2 = wr[2], w3 = wr[3];           \
      accA0 += xa * w0; accA1 += xa * w1; accA2 += xa * w2; accA3 += xa * w3; \
      accB0 += xb * w0; accB1 += xb * w1; accB2 += xb * w2; accB3 += xb * w3; \
    } }

__global__ __launch_bounds__(256)
void k_gemm1(const float* __restrict__ X, const float* __restrict__ W1,
             float* __restrict__ hpart) {
    __shared__ float wlds[RW * NH];                 // 10240 B
    __shared__ float sX[4][TILE_R * SXS];           // 4 x 10240 B
    const int wid = threadIdx.x >> 6;
    const int t   = threadIdx.x & 63;
    const int rb    = blockIdx.x % NRBV;
    const int split = blockIdx.x / NRBV;

    // ---- stage this split's W1 slice into LDS (zero-fill past K_IN) ----
    {
        const f4* W1v = (const f4*)W1;              // each W1 row = 4 f4
        const int wbase = split * RW;
#pragma unroll
        for (int r = 0; r < 3; ++r) {               // ceil(640/256) = 3 iters
            int idx = r * 256 + threadIdx.x;        // f4 index into wlds
            if (idx < RW * 4) {
                int krow = wbase + (idx >> 2);
                f4 wv = 0.f;
                if (krow < K_IN) wv = W1v[krow * 4 + (idx & 3)];
                ((f4*)wlds)[idx] = wv;
            }
        }
    }
    __syncthreads();

    const int tile = rb * 4 + wid;
    if (tile >= NTILEV) return;                     // wave-uniform, after sync
    const int base = tile * TILE_R;
    const int Lq = t & 3;                           // 16B granule within 64B
    const int Lr = t >> 2;                          // row group 0..15

    // 8 staging row pointers (clamped); each already offset by this lane's kq
    const float* xp0 = X + (size_t)min(base + Lr +   0, N_NODES - 1) * K_IN + 4 * Lq;
    const float* xp1 = X + (size_t)min(base + Lr +  16, N_NODES - 1) * K_IN + 4 * Lq;
    const float* xp2 = X + (size_t)min(base + Lr +  32, N_NODES - 1) * K_IN + 4 * Lq;
    const float* xp3 = X + (size_t)min(base + Lr +  48, N_NODES - 1) * K_IN + 4 * Lq;
    const float* xp4 = X + (size_t)min(base + Lr +  64, N_NODES - 1) * K_IN + 4 * Lq;
    const float* xp5 = X + (size_t)min(base + Lr +  80, N_NODES - 1) * K_IN + 4 * Lq;
    const float* xp6 = X + (size_t)min(base + Lr +  96, N_NODES - 1) * K_IN + 4 * Lq;
    const float* xp7 = X + (size_t)min(base + Lr + 112, N_NODES - 1) * K_IN + 4 * Lq;

    float* xbuf = sX[wid];
    float* xbw  = xbuf + Lr * SXS + 4 * Lq;         // write base (granule 0)
    const float* xra = xbuf + t * SXS;              // read row t
    const float* xrb = xbuf + (t + 64) * SXS;       // read row t+64

    f4 accA0 = 0.f, accA1 = 0.f, accA2 = 0.f, accA3 = 0.f;
    f4 accB0 = 0.f, accB1 = 0.f, accB2 = 0.f, accB3 = 0.f;

    f4 sP0, sP1, sP2, sP3, sP4, sP5, sP6, sP7;      // named stage sets
    f4 sQ0, sQ1, sQ2, sQ3, sQ4, sQ5, sQ6, sQ7;

    const int k0 = split * RW;                      // first k of this split
    LOADG(k0, sP0, sP1, sP2, sP3, sP4, sP5, sP6, sP7)

#pragma unroll 1
    for (int j = 0; j < CPS / 2; ++j) {
        const int ke = k0 + 2 * j * TK;             // even chunk k-offset
        // stage even chunk, prefetch odd chunk
        WRITE_SET(sP0, sP1, sP2, sP3, sP4, sP5, sP6, sP7)
        LOADG(ke + TK, sQ0, sQ1, sQ2, sQ3, sQ4, sQ5, sQ6, sQ7)
        __builtin_amdgcn_wave_barrier();
        READ_FMA(2 * j)
        __builtin_amdgcn_wave_barrier();
        // stage odd chunk, prefetch next even chunk
        WRITE_SET(sQ0, sQ1, sQ2, sQ3, sQ4, sQ5, sQ6, sQ7)
        if (j + 1 < CPS / 2) {
            LOADG(ke + 2 * TK, sP0, sP1, sP2, sP3, sP4, sP5, sP6, sP7)
        }
        __builtin_amdgcn_wave_barrier();
        READ_FMA(2 * j + 1)
        __builtin_amdgcn_wave_barrier();
    }

    const size_t sb = (size_t)split * N_NODES;
    if (base + t < N_NODES) {
        f4* hp = (f4*)(hpart + (sb + base + t) * NH);
        hp[0] = accA0; hp[1] = accA1; hp[2] = accA2; hp[3] = accA3;
    }
    if (base + 64 + t < N_NODES) {
        f4* hp = (f4*)(hpart + (sb + base + 64 + t) * NH);
        hp[0] = accB0; hp[1] = accB1; hp[2] = accB2; hp[3] = accB3;
    }
}

// ---------------- K3: h = norm_src * sum_s hpart[s] ----------------
__global__ __launch_bounds__(256)
void k_reduce(const float* __restrict__ hpart, const int* __restrict__ deg_out,
              float* __restrict__ h) {
    int idx = blockIdx.x * 256 + threadIdx.x;   // f4 index
    if (idx >= N_NODES * 4) return;
    f4 a = 0.f;
#pragma unroll
    for (int s = 0; s < KSPLIT; ++s)
        a += ((const f4*)hpart)[(size_t)s * N_NODES * 4 + idx];
    float ns = rsqrtf((float)max(deg_out[idx >> 2], 1));
    ((f4*)h)[idx] = a * ns;
}

// ---------------- K4: gather layer1 + relu + fused (.. @ W2) ----------------
__global__ __launch_bounds__(256)
void k_layer1(const float* __restrict__ h, const int* __restrict__ adj,
              const int* __restrict__ cnt, const int* __restrict__ deg_out,
              const float* __restrict__ W2, const float* __restrict__ b1,
              float* __restrict__ g) {
    const int lane = threadIdx.x & 63;
    const int wid  = threadIdx.x >> 6;
    const int d    = blockIdx.x * 4 + wid;
    if (d >= N_NODES) return;                  // wave-uniform
    const int j4 = lane & 3, slot = lane >> 2;
    const int start = d * SLOT;
    const int deg   = min(cnt[d], SLOT);
    const int end   = start + deg;
    f4 agg = 0.f;
    for (int p = start + slot; p < end; p += 16) {
        int s = adj[p];
        agg += ((const f4*)h)[s * 4 + j4];
    }
#pragma unroll
    for (int off = 4; off < 64; off <<= 1) {
        agg[0] += __shfl_xor(agg[0], off);
        agg[1] += __shfl_xor(agg[1], off);
        agg[2] += __shfl_xor(agg[2], off);
        agg[3] += __shfl_xor(agg[3], off);
    }
    __shared__ float st[4][NH];
    const float nd = rsqrtf((float)max(deg, 1));
    if (slot == 0) {
        f4 bb = ((const f4*)b1)[j4];
        f4 tj;
        tj[0] = fmaxf(fmaf(agg[0], nd, bb[0]), 0.f);
        tj[1] = fmaxf(fmaf(agg[1], nd, bb[1]), 0.f);
        tj[2] = fmaxf(fmaf(agg[2], nd, bb[2]), 0.f);
        tj[3] = fmaxf(fmaf(agg[3], nd, bb[3]), 0.f);
        ((f4*)st[wid])[j4] = tj;
    }
    __builtin_amdgcn_wave_barrier();
    float r = 0.f;
    if (lane < NO) {
#pragma unroll
        for (int qq = 0; qq < NH; ++qq)
            r = fmaf(st[wid][qq], W2[qq * NO + lane], r);
    }
    if (lane < 8) {
        float ns = rsqrtf((float)max(deg_out[d], 1));
        g[(size_t)d * 8 + lane] = (lane < NO) ? ns * r : 0.f;  // zero pad slot
    }
}

// ---------------- K5: gather layer2 -> out ----------------
__global__ __launch_bounds__(256)
void k_layer2(const float* __restrict__ g, const int* __restrict__ adj,
              const int* __restrict__ cnt, const float* __restrict__ b2,
              float* __restrict__ out) {
    const int lane = threadIdx.x & 63;
    const int wid  = threadIdx.x >> 6;
    const int d    = blockIdx.x * 4 + wid;
    if (d >= N_NODES) return;
    const int o4 = lane & 1, slot = lane >> 1;
    const int start = d * SLOT;
    const int deg   = min(cnt[d], SLOT);
    const int end   = start + deg;
    f4 agg = 0.f;
    for (int p = start + slot; p < end; p += 32) {
        int s = adj[p];
        agg += ((const f4*)g)[s * 2 + o4];
    }
#pragma unroll
    for (int off = 2; off < 64; off <<= 1) {
        agg[0] += __shfl_xor(agg[0], off);
        agg[1] += __shfl_xor(agg[1], off);
        agg[2] += __shfl_xor(agg[2], off);
        agg[3] += __shfl_xor(agg[3], off);
    }
    // even lanes hold o=0..3 sums, odd lanes hold o=4..7 sums
    const int sl = lane >> 2;
    float v0 = __shfl(agg[0], sl);
    float v1 = __shfl(agg[1], sl);
    float v2 = __shfl(agg[2], sl);
    float v3 = __shfl(agg[3], sl);
    int cm = lane & 3;
    float v = (cm == 0) ? v0 : (cm == 1) ? v1 : (cm == 2) ? v2 : v3;
    if (lane < NO) {
        float nd = rsqrtf((float)max(deg, 1));
        out[(size_t)d * NO + lane] = fmaf(v, nd, b2[lane]);
    }
}

extern "C" void kernel_launch(void* const* d_in, const int* in_sizes, int n_in,
                              void* d_out, int out_size, void* d_ws, size_t ws_size,
                              hipStream_t stream) {
    const float* X   = (const float*)d_in[0];
    const int*   src = (const int*)d_in[1];
    const int*   dst = (const int*)d_in[2];
    const float* W1  = (const float*)d_in[3];
    const float* b1  = (const float*)d_in[4];
    const float* W2  = (const float*)d_in[5];
    const float* b2  = (const float*)d_in[6];
    float* out = (float*)d_out;

    char* w = (char*)d_ws;
    float* hpart    = (float*)w;  w += (size_t)KSPLIT * N_NODES * NH * 4; // 57.6 MB
    float* h        = (float*)w;  w += (size_t)N_NODES * NH * 4;          // 6.4 MB
    float* g        = (float*)w;  w += (size_t)N_NODES * 8 * 4;           // 3.2 MB
    int*   adj      = (int*)w;    w += (size_t)N_NODES * SLOT * 4;        // 38.4 MB
    int*   deg_out_a= (int*)w;    w += (size_t)N_NODES * 4;
    int*   cnt      = (int*)w;    w += (size_t)N_NODES * 4;

    hipMemsetAsync(deg_out_a, 0, (size_t)N_NODES * 2 * 4, stream);

    k_build <<<2048, 256, 0, stream>>>(src, dst, deg_out_a, cnt, adj);
    k_gemm1 <<<NRBV * KSPLIT, 256, 0, stream>>>(X, W1, hpart);
    k_reduce<<<(N_NODES * 4 + 255) / 256, 256, 0, stream>>>(hpart, deg_out_a, h);
    k_layer1<<<(N_NODES + 3) / 4, 256, 0, stream>>>(h, adj, cnt, deg_out_a,
                                                    W2, b1, g);
    k_layer2<<<(N_NODES + 3) / 4, 256, 0, stream>>>(g, adj, cnt, b2, out);
}